// Round 15
// baseline (182.962 us; speedup 1.0000x reference)
//
#include <hip/hip_runtime.h>
#include <hip/hip_bf16.h>
#include <stdint.h>

#define NB 8
#define HH 128
#define WW 128
#define LL (HH*WW)        // 16384
#define NL (NB*LL)        // 131072

typedef __attribute__((ext_vector_type(8))) short short8;   // 8 bf16
typedef __attribute__((ext_vector_type(4))) float f32x4;

#define SEG_SLOTS 1728    // worst case 64 px x 27 items

__device__ inline short f2bf(float f) {
    __hip_bfloat16 h = __float2bfloat16(f);
    short s; __builtin_memcpy(&s, &h, 2); return s;
}

// ---------------------------------------------------------------------------
// SINGLE fused kernel: one block = one image row (128 px) of one image.
//  1) waves 0,1: depth-mask scan, emit correction items to an LDS list via
//     convergent ballot prefix sums (no atomics, no global traffic).
//  2) all waves: dense 1x1 MFMA out[64 o][row] = W1c * x[64 c][row];
//     A-fragments gathered directly from w1 (L2-hot after first blocks),
//     B via direct global loads (x is L3-resident).
//  3) barrier; 4 waves drain the LDS item list: per item one 64-lane gather
//     of x[n,:,l2], 64x64 matvec with lane=o weight gather from w_br,
//     atomicAdd into this block's own out row (row-exclusive => L2-local).
// mfma_f32_16x16x32_bf16 layouts (guide-verified):
//   A: row=lane&15, k=(lane>>4)*8+j ; B: col=lane&15, same k
//   D: col=lane&15, row=(lane>>4)*4+reg
// ---------------------------------------------------------------------------
__global__ __launch_bounds__(256, 6) void fused_kernel(
    const float* __restrict__ x, const float* __restrict__ depth,
    const float* __restrict__ fx, const float* __restrict__ w0,
    const float* __restrict__ w1, const float* __restrict__ w2,
    float* __restrict__ out)
{
    __shared__ unsigned lds_list[2 * SEG_SLOTS];   // 13.5 KB
    __shared__ unsigned lds_cnt[2];
    __shared__ float    xs[4][64];                 // per-wave gather buffer

    const int tid  = threadIdx.x;
    const int lane = tid & 63;
    const int wid  = tid >> 6;                // 0..3
    const int jcol = lane & 15;
    const int g    = lane >> 4;               // 0..3 (k-group)

    const int b      = blockIdx.x;
    const int n      = b >> 7;                // 128 blocks per image
    const int px_blk = (b & 127) << 7;        // = row h * 128

    const float* __restrict__ xb = x + ((long)n << 20);

    // ---- (1) mask scan, waves 0,1: emit to LDS list ----
    if (wid < 2) {
        const int ll = (wid << 6) + lane;     // block-local pixel 0..127
        const int l  = px_blk + ll;
        const int h  = l >> 7;
        const int w  = l & (WW - 1);
        const float* dptr = depth + (n << 14);
        float center = dptr[l];
        float grid = center / fx[n];          // PIXEL_SIZE == 1.0
        float half_ = 0.5f * grid;
        float cpg = center + grid;
        float cmg = center - grid;

        int base = 0;
        const unsigned long long lt = (1ull << lane) - 1ull;
        unsigned* seg = lds_list + wid * SEG_SLOTS;

        #pragma unroll
        for (int kh = 0; kh < 3; ++kh) {
            int hh = h + kh - 1;
            #pragma unroll
            for (int kw = 0; kw < 3; ++kw) {
                int ww = w + kw - 1;
                int kkid = kh * 3 + kw;
                bool inb = (hh >= 0) & (hh < HH) & (ww >= 0) & (ww < WW);
                int hc = hh < 0 ? 0 : (hh > 127 ? 127 : hh);
                int wc = ww < 0 ? 0 : (ww > 127 ? 127 : ww);
                float d = dptr[(hc << 7) + wc];   // clamped, always safe
                bool m[3];
                m[0] = inb && (fabsf(d - cpg)    <= half_);
                m[1] = inb && (fabsf(d - center) <= half_) && (kkid != 4);
                m[2] = inb && (fabsf(d - cmg)    <= half_);
                #pragma unroll
                for (int br = 0; br < 3; ++br) {
                    unsigned long long bal = __ballot(m[br]);
                    if (m[br]) {
                        int slot = base + (int)__popcll(bal & lt);
                        seg[slot] = ((unsigned)ll << 6) | ((unsigned)kkid << 2) | (unsigned)br;
                    }
                    base += (int)__popcll(bal);
                }
            }
        }
        if (lane == 0) lds_cnt[wid] = (unsigned)base;
    }

    // ---- (2) dense: A frags direct from w1 (o=ot*16+jcol, c=s*32+g*8+j) ----
    short8 afr[4][2];
    #pragma unroll
    for (int ot = 0; ot < 4; ++ot)
        #pragma unroll
        for (int s = 0; s < 2; ++s) {
            short8 a;
            #pragma unroll
            for (int j = 0; j < 8; ++j) {
                int o = (ot << 4) + jcol;
                int c = (s << 5) + (g << 3) + j;
                a[j] = f2bf(w1[o * 576 + c * 9 + 4]);
            }
            afr[ot][s] = a;
        }

    f32x4 acc[4][2];
    #pragma unroll
    for (int ot = 0; ot < 4; ++ot)
        #pragma unroll
        for (int pt = 0; pt < 2; ++pt)
            acc[ot][pt] = (f32x4){0.f, 0.f, 0.f, 0.f};

    const int pxw = px_blk + (wid << 5);      // wave's 32-px strip
    #pragma unroll
    for (int pt = 0; pt < 2; ++pt) {
        const int px = pxw + (pt << 4) + jcol;
        float xf[2][8];
        #pragma unroll
        for (int s = 0; s < 2; ++s)
            #pragma unroll
            for (int j = 0; j < 8; ++j)
                xf[s][j] = xb[((long)((s << 5) + (g << 3) + j) << 14) + px];

        short8 bfr[2];
        #pragma unroll
        for (int s = 0; s < 2; ++s)
            #pragma unroll
            for (int j = 0; j < 8; ++j)
                bfr[s][j] = f2bf(xf[s][j]);

        #pragma unroll
        for (int s = 0; s < 2; ++s)
            #pragma unroll
            for (int ot = 0; ot < 4; ++ot)
                acc[ot][pt] = __builtin_amdgcn_mfma_f32_16x16x32_bf16(
                    afr[ot][s], bfr[s], acc[ot][pt], 0, 0, 0);
    }

    float* __restrict__ ob = out + ((long)n << 20);
    #pragma unroll
    for (int ot = 0; ot < 4; ++ot)
        #pragma unroll
        for (int pt = 0; pt < 2; ++pt)
            #pragma unroll
            for (int r = 0; r < 4; ++r) {
                int o = (ot << 4) + (g << 2) + r;
                ob[((long)o << 14) + pxw + (pt << 4) + jcol] = acc[ot][pt][r];
            }

    // ---- (3) drain correction items ----
    __syncthreads();

    #pragma unroll
    for (int s = 0; s < 2; ++s) {
        const unsigned c_ = lds_cnt[s];
        for (unsigned i = (unsigned)wid; i < c_; i += 4) {
            unsigned item = lds_list[s * SEG_SLOTS + i];
            int br   = item & 3;
            int kkid = (item >> 2) & 15;
            int l    = px_blk + (int)(item >> 6);
            int dh = kkid / 3 - 1, dw = kkid % 3 - 1;
            int l2 = l + dh * WW + dw;            // in-image by construction

            xs[wid][lane] = xb[((long)lane << 14) + l2];   // 64-lane gather

            const float* wb = (br == 0) ? w0 : ((br == 1) ? w1 : w2);
            const float* wt = wb + lane * 576 + kkid;      // lane = o, L2-hot
            float a = 0.f;
            #pragma unroll 8
            for (int c = 0; c < 64; ++c)
                a = fmaf(wt[c * 9], xs[wid][c], a);

            atomicAdd(&ob[((long)lane << 14) + l], a);    // own row: L2-local
        }
    }
}

// ---------------------------------------------------------------------------
extern "C" void kernel_launch(void* const* d_in, const int* in_sizes, int n_in,
                              void* d_out, int out_size, void* d_ws, size_t ws_size,
                              hipStream_t stream)
{
    const float* x     = (const float*)d_in[0];
    const float* depth = (const float*)d_in[1];
    const float* fx    = (const float*)d_in[2];
    const float* w0    = (const float*)d_in[3];
    const float* w1    = (const float*)d_in[4];
    const float* w2    = (const float*)d_in[5];
    float* out = (float*)d_out;

    fused_kernel<<<NL / 128, 256, 0, stream>>>(x, depth, fx, w0, w1, w2, out);
}

// Round 16
// 114.010 us; speedup vs baseline: 1.6048x; 1.6048x over previous
//
#include <hip/hip_runtime.h>
#include <hip/hip_bf16.h>
#include <stdint.h>

#define NB 8
#define HH 128
#define WW 128
#define LL (HH*WW)        // 16384
#define NL (NB*LL)        // 131072

typedef __attribute__((ext_vector_type(8))) short short8;   // 8 bf16
typedef __attribute__((ext_vector_type(4))) float f32x4;

// workspace layout (ws_size = 256 MiB, proven by round-6 fill counters)
#define WS_WT_OFF      256                            // fp32 [b][kk][c][o]
#define WS_WT_FLOATS   (27*4096)
#define WS_WA_OFF      (WS_WT_OFF + WS_WT_FLOATS*4)   // bf16 [64 o][64 c] w1 center
#define SEG_SLOTS      1728                           // worst case 64 px x 27

__device__ inline short f2bf(float f) {
    __hip_bfloat16 h = __float2bfloat16(f);
    short s; __builtin_memcpy(&s, &h, 2); return s;
}

// ---------------------------------------------------------------------------
// Prep: wT fp32 [b][kk][c][o] (correction matvecs); wA bf16 [o][c] (dense A).
// One-time re-layout so the hot kernel reads PACKED fragments (1 line/lane-
// group instead of 1 line/lane — round-15 lesson).
// ---------------------------------------------------------------------------
__global__ __launch_bounds__(256) void prep_kernel(
    const float* __restrict__ w0, const float* __restrict__ w1,
    const float* __restrict__ w2, float* __restrict__ wT,
    short* __restrict__ wA)
{
    int e = blockIdx.x * 256 + threadIdx.x;
    if (e < WS_WT_FLOATS) {
        int b  = e / 36864;            // 9*4096
        int r  = e - b * 36864;
        int kk = r >> 12;
        int q  = r & 4095;
        int c  = q >> 6;
        int o  = q & 63;
        const float* w = (b == 0) ? w0 : ((b == 1) ? w1 : w2);
        wT[e] = w[o * 576 + c * 9 + kk];   // (O,C,3,3) layout
    }
    if (e < 4096) {                        // wA[o][c] = w1[o][c][1][1]
        int o = e >> 6, c = e & 63;
        wA[e] = f2bf(w1[o * 576 + c * 9 + 4]);
    }
}

// ---------------------------------------------------------------------------
// FUSED kernel: one block = one image row (128 px) of one image.
//  1) waves 0,1: depth-mask scan, emit correction items to an LDS list via
//     convergent ballot prefix sums (no global traffic, no atomics).
//  2) all waves: dense 1x1 MFMA out[64 o][row] = W1c * x[64 c][row], with
//     DIRECT global B-loads (x is L3-resident; verified round-9 path).
//  3) barrier; all 4 waves drain the LDS item list: per item one 64-lane
//     gather of x[n,:,l2], 64x64 matvec, atomicAdd into this block's own
//     out row (row-exclusive => L2-local atomics).
// mfma_f32_16x16x32_bf16 layouts (guide-verified):
//   A: row=lane&15, k=(lane>>4)*8+j ; B: col=lane&15, same k
//   D: col=lane&15, row=(lane>>4)*4+reg
// ---------------------------------------------------------------------------
__global__ __launch_bounds__(256, 6) void fused_kernel(
    const float* __restrict__ x, const float* __restrict__ depth,
    const float* __restrict__ fx, const short* __restrict__ wA,
    const float* __restrict__ wT, float* __restrict__ out)
{
    __shared__ unsigned lds_list[2 * SEG_SLOTS];   // 13.5 KB
    __shared__ unsigned lds_cnt[2];
    __shared__ float    xs[4][64];                 // per-wave gather buffer

    const int tid  = threadIdx.x;
    const int lane = tid & 63;
    const int wid  = tid >> 6;                // 0..3
    const int jcol = lane & 15;
    const int g    = lane >> 4;               // 0..3 (k-group)

    const int b      = blockIdx.x;
    const int n      = b >> 7;                // 128 blocks per image
    const int px_blk = (b & 127) << 7;        // = row h * 128

    const float* __restrict__ xb = x + ((long)n << 20);

    // ---- (1) mask scan, waves 0,1: emit to LDS list ----
    if (wid < 2) {
        const int ll = (wid << 6) + lane;     // block-local pixel 0..127
        const int l  = px_blk + ll;
        const int h  = l >> 7;
        const int w  = l & (WW - 1);
        const float* dptr = depth + (n << 14);
        float center = dptr[l];
        float grid = center / fx[n];          // PIXEL_SIZE == 1.0
        float half_ = 0.5f * grid;
        float cpg = center + grid;
        float cmg = center - grid;

        int base = 0;
        const unsigned long long lt = (1ull << lane) - 1ull;
        unsigned* seg = lds_list + wid * SEG_SLOTS;

        #pragma unroll
        for (int kh = 0; kh < 3; ++kh) {
            int hh = h + kh - 1;
            #pragma unroll
            for (int kw = 0; kw < 3; ++kw) {
                int ww = w + kw - 1;
                int kkid = kh * 3 + kw;
                bool inb = (hh >= 0) & (hh < HH) & (ww >= 0) & (ww < WW);
                int hc = hh < 0 ? 0 : (hh > 127 ? 127 : hh);
                int wc = ww < 0 ? 0 : (ww > 127 ? 127 : ww);
                float d = dptr[(hc << 7) + wc];   // clamped, always safe
                bool m[3];
                m[0] = inb && (fabsf(d - cpg)    <= half_);
                m[1] = inb && (fabsf(d - center) <= half_) && (kkid != 4);
                m[2] = inb && (fabsf(d - cmg)    <= half_);
                #pragma unroll
                for (int br = 0; br < 3; ++br) {
                    unsigned long long bal = __ballot(m[br]);
                    if (m[br]) {
                        int slot = base + (int)__popcll(bal & lt);
                        seg[slot] = ((unsigned)ll << 6) | ((unsigned)kkid << 2) | (unsigned)br;
                    }
                    base += (int)__popcll(bal);
                }
            }
        }
        if (lane == 0) lds_cnt[wid] = (unsigned)base;
    }

    // ---- (2) dense: A frags from wA; B via direct global loads (r9 path) ----
    short8 afr[4][2];
    #pragma unroll
    for (int ot = 0; ot < 4; ++ot)
        #pragma unroll
        for (int s = 0; s < 2; ++s)
            afr[ot][s] = *(const short8*)(wA + (((ot << 4) + jcol) << 6) + (s << 5) + (g << 3));

    f32x4 acc[4][2];
    #pragma unroll
    for (int ot = 0; ot < 4; ++ot)
        #pragma unroll
        for (int pt = 0; pt < 2; ++pt)
            acc[ot][pt] = (f32x4){0.f, 0.f, 0.f, 0.f};

    const int pxw = px_blk + (wid << 5);      // wave's 32-px strip
    #pragma unroll
    for (int pt = 0; pt < 2; ++pt) {
        const int px = pxw + (pt << 4) + jcol;
        float xf[2][8];
        #pragma unroll
        for (int s = 0; s < 2; ++s)
            #pragma unroll
            for (int j = 0; j < 8; ++j)
                xf[s][j] = xb[((long)((s << 5) + (g << 3) + j) << 14) + px];

        short8 bfr[2];
        #pragma unroll
        for (int s = 0; s < 2; ++s)
            #pragma unroll
            for (int j = 0; j < 8; ++j)
                bfr[s][j] = f2bf(xf[s][j]);

        #pragma unroll
        for (int s = 0; s < 2; ++s)
            #pragma unroll
            for (int ot = 0; ot < 4; ++ot)
                acc[ot][pt] = __builtin_amdgcn_mfma_f32_16x16x32_bf16(
                    afr[ot][s], bfr[s], acc[ot][pt], 0, 0, 0);
    }

    float* __restrict__ ob = out + ((long)n << 20);
    #pragma unroll
    for (int ot = 0; ot < 4; ++ot)
        #pragma unroll
        for (int pt = 0; pt < 2; ++pt)
            #pragma unroll
            for (int r = 0; r < 4; ++r) {
                int o = (ot << 4) + (g << 2) + r;
                ob[((long)o << 14) + pxw + (pt << 4) + jcol] = acc[ot][pt][r];
            }

    // ---- (3) drain correction items (stores drained by barrier's vmcnt) ----
    __syncthreads();

    #pragma unroll
    for (int s = 0; s < 2; ++s) {
        const unsigned c_ = lds_cnt[s];
        for (unsigned i = (unsigned)wid; i < c_; i += 4) {
            unsigned item = lds_list[s * SEG_SLOTS + i];
            int br   = item & 3;
            int kkid = (item >> 2) & 15;
            int l    = px_blk + (int)(item >> 6);
            int dh = kkid / 3 - 1, dw = kkid % 3 - 1;
            int l2 = l + dh * WW + dw;            // in-image by construction

            xs[wid][lane] = xb[((long)lane << 14) + l2];   // 64-lane gather

            const float* wt = wT + ((br * 9 + kkid) << 12);   // [c][o], L2-hot
            float a = 0.f;
            #pragma unroll 8
            for (int c = 0; c < 64; ++c)
                a = fmaf(wt[(c << 6) + lane], xs[wid][c], a);

            atomicAdd(&ob[((long)lane << 14) + l], a);    // own row: L2-local
        }
    }
}

// ---------------------------------------------------------------------------
extern "C" void kernel_launch(void* const* d_in, const int* in_sizes, int n_in,
                              void* d_out, int out_size, void* d_ws, size_t ws_size,
                              hipStream_t stream)
{
    const float* x     = (const float*)d_in[0];
    const float* depth = (const float*)d_in[1];
    const float* fx    = (const float*)d_in[2];
    const float* w0    = (const float*)d_in[3];
    const float* w1    = (const float*)d_in[4];
    const float* w2    = (const float*)d_in[5];
    float* out = (float*)d_out;

    unsigned char* ws = (unsigned char*)d_ws;
    float* wT = (float*)(ws + WS_WT_OFF);
    short* wA = (short*)(ws + WS_WA_OFF);

    prep_kernel <<<(WS_WT_FLOATS + 255) / 256, 256, 0, stream>>>(w0, w1, w2, wT, wA);
    fused_kernel<<<NL / 128, 256, 0, stream>>>(x, depth, fx, wA, wT, out);
}